// Round 2
// 509.891 us; speedup vs baseline: 1.2193x; 1.2193x over previous
//
#include <hip/hip_runtime.h>

#define B_  8
#define T_  4096
#define C_  1024
#define TP  4098                 // T + 2 halo rows
#define NW  (1024 * 1024)        // weights per k-slice
#define NT  48                   // K tiles: 3 shifts x (1024/64)

typedef __bf16 bf16x8 __attribute__((ext_vector_type(8)));
typedef float  f32x4  __attribute__((ext_vector_type(4)));

__device__ __forceinline__ unsigned short f2bf_rne(float f) {
    unsigned u = __float_as_uint(f);
    u += 0x7FFFu + ((u >> 16) & 1u);
    return (unsigned short)(u >> 16);
}

// async global->LDS, 16B per lane; LDS dest = wave-uniform base + lane*16
#define GLOAD16(g, l)                                                        \
    __builtin_amdgcn_global_load_lds(                                        \
        (const __attribute__((address_space(1))) void*)(g),                  \
        (__attribute__((address_space(3))) void*)(l), 16, 0, 0)

// ---------------------------------------------------------------- init
__global__ __launch_bounds__(256) void init_kernel(
    float* __restrict__ gamma_x, double* __restrict__ wsum,
    unsigned short* __restrict__ xq) {
    const int i = blockIdx.x * 256 + threadIdx.x;   // grid 64*256 = 16384
    if (i < 8192) gamma_x[i] = 0.0f;                // [B][C] absmax accumulators
    if (i == 0) *wsum = 0.0;
    const int r16 = i >> 10;                        // 0..15 pad rows
    const int b = r16 >> 1, side = r16 & 1;
    xq[((size_t)b * TP + (size_t)side * (TP - 1)) * C_ + (i & 1023)] = 0;
}

// ---------------------------------------------------------------- fused LN stats + absmax (one x pass)
// grid 1024 blocks x 256 thr; block = 32 rows; wave w: 8 rows sequential.
// lane l holds cols [l*16, l*16+16) in regs; butterfly-reduce gives all
// lanes identical mu/rstd; per-channel max folded immediately (no re-read).
__global__ __launch_bounds__(256) void stats_absmax_kernel(
    const float* __restrict__ x, const float* __restrict__ lng,
    const float* __restrict__ lnb, float2* __restrict__ stats,
    float* __restrict__ gamma_x) {
    const int tid = threadIdx.x;
    const int w = tid >> 6, l = tid & 63;
    const int row0 = blockIdx.x * 32;               // b*T + t, 4096%32==0: no b-straddle
    const int b = row0 >> 12;
    __shared__ unsigned lmax[1024];
#pragma unroll
    for (int k = 0; k < 4; ++k) lmax[tid + k * 256] = 0u;
    __syncthreads();

    const int c0 = l * 16;
    float gv[16], bv[16], m[16];
#pragma unroll
    for (int j = 0; j < 4; ++j) {
        *(float4*)&gv[j * 4] = *(const float4*)(lng + c0 + j * 4);
        *(float4*)&bv[j * 4] = *(const float4*)(lnb + c0 + j * 4);
    }
#pragma unroll
    for (int j = 0; j < 16; ++j) m[j] = 0.0f;

#pragma unroll 2
    for (int rr = 0; rr < 8; ++rr) {
        const int row = row0 + w * 8 + rr;
        const float* xr = x + (size_t)row * C_ + c0;
        float v[16];
#pragma unroll
        for (int j = 0; j < 4; ++j) *(float4*)&v[j * 4] = *(const float4*)(xr + j * 4);
        float s = 0.0f, s2 = 0.0f;
#pragma unroll
        for (int j = 0; j < 16; ++j) { s += v[j]; s2 += v[j] * v[j]; }
#pragma unroll
        for (int off = 1; off < 64; off <<= 1) {
            s  += __shfl_xor(s,  off, 64);
            s2 += __shfl_xor(s2, off, 64);
        }
        const float mu   = s * (1.0f / C_);
        const float var  = fmaxf(s2 * (1.0f / C_) - mu * mu, 0.0f);
        const float rstd = 1.0f / sqrtf(var + 1e-5f);
        if (l == 0) stats[row] = make_float2(mu, rstd);
#pragma unroll
        for (int j = 0; j < 16; ++j)
            m[j] = fmaxf(m[j], fabsf((v[j] - mu) * rstd * gv[j] + bv[j]));
    }
    // m >= 0 so uint compare == float compare
#pragma unroll
    for (int j = 0; j < 16; ++j) atomicMax(&lmax[c0 + j], __float_as_uint(m[j]));
    __syncthreads();
#pragma unroll
    for (int k = 0; k < 4; ++k) {
        const int c = tid + k * 256;
        atomicMax((unsigned*)(gamma_x + b * C_ + c), lmax[c]);
    }
}

// ---------------------------------------------------------------- sum |W|
__global__ __launch_bounds__(256) void wsum_kernel(
    const float* __restrict__ W, double* __restrict__ wsum) {
    size_t i = ((size_t)blockIdx.x * 256 + threadIdx.x) * 8;  // grid 1536
    float4 a  = *(const float4*)(W + i);
    float4 b4 = *(const float4*)(W + i + 4);
    float s = fabsf(a.x) + fabsf(a.y) + fabsf(a.z) + fabsf(a.w)
            + fabsf(b4.x) + fabsf(b4.y) + fabsf(b4.z) + fabsf(b4.w);
#pragma unroll
    for (int off = 32; off > 0; off >>= 1) s += __shfl_down(s, off, 64);
    __shared__ float ps[4];
    const int wave = threadIdx.x >> 6, lane = threadIdx.x & 63;
    if (lane == 0) ps[wave] = s;
    __syncthreads();
    if (threadIdx.x == 0) atomicAdd(wsum, (double)((ps[0] + ps[1]) + (ps[2] + ps[3])));
}

// ---------------------------------------------------------------- weight quant + repack wq[k][o][i]
__global__ __launch_bounds__(256) void wquant_kernel(
    const float* __restrict__ W, const double* __restrict__ wsum,
    unsigned short* __restrict__ wq, float* __restrict__ beta_out) {
    const int gid = blockIdx.x * 256 + threadIdx.x;   // (o,i) pair, grid 4096
    const float beta = fmaxf((float)(*wsum * (1.0 / 3145728.0)), 1e-5f);
    if (gid == 0) *beta_out = beta;
    const float* wp = W + (size_t)gid * 3;
#pragma unroll
    for (int k = 0; k < 3; ++k) {
        float s  = wp[k] / beta;                      // ref: clip then round
        float r  = rintf(fminf(fmaxf(s, -1.0f), 1.0f));
        wq[(size_t)k * NW + gid] = f2bf_rne(r);       // {-1,0,1} exact in bf16
    }
}

// ---------------------------------------------------------------- activation quant -> padded xq
__device__ __forceinline__ unsigned short quant1(float xv, float2 s, float g,
                                                 float be, float gam) {
    float xn = (xv - s.x) * s.y * g + be;
    float sc = 127.0f / fmaxf(gam, 1e-5f);
    float r  = rintf(xn * sc);                        // ref: round then clip
    r = fminf(fmaxf(r, -127.0f), 127.0f);
    return f2bf_rne(r);                               // integer |r|<=127: exact
}

__global__ __launch_bounds__(256) void xquant_kernel(
    const float* __restrict__ x, const float2* __restrict__ stats,
    const float* __restrict__ lng, const float* __restrict__ lnb,
    const float* __restrict__ gamma_x, unsigned short* __restrict__ xq) {
    const int row = blockIdx.x;                       // b*T + t, grid 32768
    const int b = row >> 12, t = row & 4095;
    const float2 s = stats[row];
    const int c = threadIdx.x * 4;
    float4 xv = *(const float4*)(x + (size_t)row * C_ + c);
    float4 gv = *(const float4*)(lng + c);
    float4 bv = *(const float4*)(lnb + c);
    float4 gm = *(const float4*)(gamma_x + b * C_ + c);
    ushort4 qv;
    qv.x = quant1(xv.x, s, gv.x, bv.x, gm.x);
    qv.y = quant1(xv.y, s, gv.y, bv.y, gm.y);
    qv.z = quant1(xv.z, s, gv.z, bv.z, gm.z);
    qv.w = quant1(xv.w, s, gv.w, bv.w, gm.w);
    *(ushort4*)(xq + ((size_t)b * TP + t + 1) * C_ + c) = qv;
}

// ---------------------------------------------------------------- conv-as-GEMM: 256x256 tile, 8-wave,
// 4-phase/K-tile pipeline with counted vmcnt(8) (never 0 in main loop), K-half-major
// swizzled LDS (conflict-free ds_read_b128), setprio around MFMA, XCD-bijective grid.
//
// K stream: 48 tiles of BK=64 (3 conv shifts x 16); A address advance is a uniform
// +64 elements/tile (shift step = +1 padded row - 15*64 = +64).
// LDS [buf][khalf][256][32] bf16: tile kt in buf[kt&1]; k0 staged at (kt-2).P2/P3,
// k1 at (kt-1).P0/P1 -> every wait point has exactly 8 younger loads in flight.
// Granule swizzle g ^= (row>>1)&3 applied to per-lane GLOBAL src (linear LDS dest,
// rule 21) and to ds_read addr: uniform 8 accesses/bank = b128 minimum.
__global__ __launch_bounds__(512, 2) void gemm_kernel(
    const unsigned short* __restrict__ xq,   // [B][TP][C] bf16 (padded)
    const unsigned short* __restrict__ wq,   // [3][O][I] bf16 ternary
    const float* __restrict__ gamma_x,       // [B][C]
    const float* __restrict__ beta_p,        // scalar
    float* __restrict__ out) {               // [B][T][O] fp32
    __shared__ __align__(16) unsigned short sA[2][2][8192];  // 64 KiB
    __shared__ __align__(16) unsigned short sB[2][2][8192];  // 64 KiB

    const int tid = threadIdx.x;
    const int w   = tid >> 6;                 // wave 0..7 (2M x 4N)
    const int l   = tid & 63;
    const int q   = l >> 4;                   // k-granule 0..3
    const int lr  = l & 15;                   // fragment row
    const int g8    = (q ^ ((lr >> 1) & 3)) * 8;           // read granule (swizzled)
    const int srcg8 = ((l & 3) ^ ((l >> 3) & 3)) * 8;      // stage src granule (same involution)

    // XCD-bijective decode: 512 blocks = 8 xcd-slots x 64; 4 n-tiles of one
    // (b,mt) A-panel share an XCD-slot (L2 reuse of A).
    const int d  = blockIdx.x;
    const int gg = (d & 7) + ((d >> 5) << 3);   // (b,mt) group 0..127
    const int nt = (d >> 3) & 3;
    const int b  = gg >> 4;
    const int t0 = (gg & 15) << 8;
    const int n0 = nt << 8;

    const int wm = (w >> 2) * 128;            // wave M offset (2 x 128)
    const int wn = (w & 3) * 64;              // wave N offset (4 x 64)

    const unsigned short* A0 = xq + (size_t)(b * TP + t0) * C_;
    const unsigned short* Bq = wq + (size_t)n0 * C_;

    f32x4 acc[8][4] = {};

#define STG(DST, GP) do {                                                         \
        GLOAD16((GP) + (size_t)(w * 16 + (l >> 2)) * C_ + srcg8, (DST) + w * 512);\
        GLOAD16((GP) + (size_t)(w * 16 + (l >> 2) + 128) * C_ + srcg8,            \
                (DST) + 4096 + w * 512);                                          \
    } while (0)
#define STG_A(S, KH) STG(&sA[(S) & 1][KH][0], A0 + (S) * 64 + (KH) * 32)
#define STG_B(S, KH) STG(&sB[(S) & 1][KH][0],                                     \
        Bq + (size_t)((S) >> 4) * NW + ((S) & 15) * 64 + (KH) * 32)

#define VM8 asm volatile("s_waitcnt vmcnt(8)" ::: "memory")
#define VM4 asm volatile("s_waitcnt vmcnt(4)" ::: "memory")
#define VM0 asm volatile("s_waitcnt vmcnt(0)" ::: "memory")
#define VMX do {} while (0)

// one phase: {ds_read frags | stage-issue} -> barrier -> lgkmcnt(0) -> 16 MFMA -> [vmcnt] -> barrier
#define PHASE(BU, MSET, KH, LOADB, VM, ...) do {                                  \
        bf16x8 af[4];                                                             \
        _Pragma("unroll")                                                         \
        for (int i2 = 0; i2 < 4; ++i2)                                            \
            af[i2] = *(const bf16x8*)&sA[BU][KH]                                  \
                [(wm + (MSET) * 64 + i2 * 16 + lr) * 32 + g8];                    \
        if (LOADB) {                                                              \
            _Pragma("unroll")                                                     \
            for (int ni = 0; ni < 4; ++ni)                                        \
                bfr[ni] = *(const bf16x8*)&sB[BU][KH]                             \
                    [(wn + ni * 16 + lr) * 32 + g8];                              \
        }                                                                         \
        __VA_ARGS__;                                                              \
        __builtin_amdgcn_s_barrier();                                             \
        asm volatile("s_waitcnt lgkmcnt(0)" ::: "memory");                        \
        __builtin_amdgcn_sched_barrier(0);                                        \
        __builtin_amdgcn_s_setprio(1);                                            \
        _Pragma("unroll")                                                         \
        for (int mi = 0; mi < 4; ++mi)                                            \
            _Pragma("unroll")                                                     \
            for (int ni = 0; ni < 4; ++ni)                                        \
                acc[(MSET) * 4 + mi][ni] = __builtin_amdgcn_mfma_f32_16x16x32_bf16(\
                    af[mi], bfr[ni], acc[(MSET) * 4 + mi][ni], 0, 0, 0);          \
        __builtin_amdgcn_s_setprio(0);                                            \
        VM;                                                                       \
        __builtin_amdgcn_s_barrier();                                             \
    } while (0)

// P0: mset0/k0 (+B k0 frags), stage A(kt+1).k1 | P1: mset1/k0, stage B(kt+1).k1, wait
// P2: mset0/k1 (+B k1 frags), stage A(kt+2).k0 | P3: mset1/k1, stage B(kt+2).k0, wait
#define TILE_STEP(KT, BU, DO1, DO2, VM1, VM3) do {                                \
        PHASE(BU, 0, 0, 1, VMX, { if (DO1) { STG_A((KT) + 1, 1); } });            \
        PHASE(BU, 1, 0, 0, VM1, { if (DO1) { STG_B((KT) + 1, 1); } });            \
        PHASE(BU, 0, 1, 1, VMX, { if (DO2) { STG_A((KT) + 2, 0); } });            \
        PHASE(BU, 1, 1, 0, VM3, { if (DO2) { STG_B((KT) + 2, 0); } });            \
    } while (0)

    // prologue: tile0 (k0,k1) + tile1.k0 = 12 loads; vmcnt(8) -> tile0.k0 landed
    STG_A(0, 0); STG_B(0, 0);
    STG_A(0, 1); STG_B(0, 1);
    STG_A(1, 0); STG_B(1, 0);
    VM8;
    __builtin_amdgcn_s_barrier();

    bf16x8 bfr[4];
#pragma unroll 1
    for (int kt = 0; kt < 46; kt += 2) {
        TILE_STEP(kt,     0, true, true, VM8, VM8);
        TILE_STEP(kt + 1, 1, true, true, VM8, VM8);
    }
    TILE_STEP(46, 0, true,  false, VM8, VM4);   // stop staging k0; 4 loads left
    TILE_STEP(47, 1, false, false, VM0, VMX);   // drain before final k1 reads

    // epilogue: y = acc * beta * gamma_x[b,o] / 127  (C/D: col=lane&15, row=quad*4+reg)
    const float beta = *beta_p;
#pragma unroll
    for (int ni = 0; ni < 4; ++ni) {
        const int o = n0 + wn + ni * 16 + lr;
        const float sc = beta * fmaxf(gamma_x[b * C_ + o], 1e-5f) * (1.0f / 127.0f);
#pragma unroll
        for (int mi = 0; mi < 8; ++mi) {
#pragma unroll
            for (int r = 0; r < 4; ++r) {
                const int t = t0 + wm + mi * 16 + q * 4 + r;
                out[(size_t)(b * T_ + t) * C_ + o] = acc[mi][ni][r] * sc;
            }
        }
    }
#undef STG
#undef STG_A
#undef STG_B
#undef PHASE
#undef TILE_STEP
}

// ---------------------------------------------------------------- launch
extern "C" void kernel_launch(void* const* d_in, const int* in_sizes, int n_in,
                              void* d_out, int out_size, void* d_ws, size_t ws_size,
                              hipStream_t stream) {
    const float* x   = (const float*)d_in[0];  // [8,4096,1024] fp32
    const float* lng = (const float*)d_in[1];  // [1024] fp32
    const float* lnb = (const float*)d_in[2];  // [1024] fp32
    const float* W   = (const float*)d_in[3];  // [1024,1024,3] fp32
    float* out = (float*)d_out;                // fp32 output [8,4096,1024]

    char* ws = (char*)d_ws;
    float2*         stats  = (float2*)(ws + 0);          //   262144 B
    float*          gamma  = (float*) (ws + 262144);     //    32768 B
    double*         wsum   = (double*)(ws + 294912);     //        8 B
    float*          beta   = (float*) (ws + 294920);     //        4 B (+pad)
    unsigned short* wq     = (unsigned short*)(ws + 294928);   // 6291456 B
    unsigned short* xq     = (unsigned short*)(ws + 6586384);  // 67141632 B -> 73.7 MB total

    init_kernel        <<<64,    256, 0, stream>>>(gamma, wsum, xq);
    stats_absmax_kernel<<<1024,  256, 0, stream>>>(x, lng, lnb, stats, gamma);
    wsum_kernel        <<<1536,  256, 0, stream>>>(W, wsum);
    wquant_kernel      <<<4096,  256, 0, stream>>>(W, wsum, wq, beta);
    xquant_kernel      <<<32768, 256, 0, stream>>>(x, stats, lng, lnb, gamma, xq);
    gemm_kernel        <<<dim3(512), 512, 0, stream>>>(xq, wq, gamma, beta, out);
}